// Round 3
// baseline (168.849 us; speedup 1.0000x reference)
//
#include <hip/hip_runtime.h>
#include <stdint.h>

// GCN layer, restructured via linearity of mean:
//   Y[N,512] = bf16(vf) @ [W | B]   (one bf16 GEMM, K=256)
//   out[n]   = relu(mean_k Y[nbr[n,k], 0:256] + Y[n, 256:512])

#define N_V   50000
#define KNB   16
#define D_F   256
#define H_F   256
#define HK2   512            // Y columns
#define NPAD  50048          // N rounded up to 64

typedef __bf16 bf16x8 __attribute__((ext_vector_type(8)));
typedef float  f32x4  __attribute__((ext_vector_type(4)));

static __device__ __forceinline__ unsigned short f2bf(float f) {
    union { float f; unsigned u; } v; v.f = f;
    unsigned u = v.u;
    u += 0x7fffu + ((u >> 16) & 1u);   // round-to-nearest-even
    return (unsigned short)(u >> 16);
}
static __device__ __forceinline__ float bf2f(unsigned short u) {
    union { unsigned u; float f; } v; v.u = ((unsigned)u) << 16; return v.f;
}
static __device__ __forceinline__ void load16(const void* g, void* l) {
    __builtin_amdgcn_global_load_lds(
        (__attribute__((address_space(1))) void*)g,
        (__attribute__((address_space(3))) void*)l, 16, 0, 0);
}

// ---------------- kernel 1: W,B -> bf16 transposed WBt[512 h][256 k] ------
__global__ __launch_bounds__(256) void wbt_convert(
    const float* __restrict__ W, const float* __restrict__ Bm,
    unsigned short* __restrict__ WBt) {
    __shared__ unsigned short t[32][33];
    const int k0 = blockIdx.x * 32;                // 0..224
    const int h0 = blockIdx.y * 32;                // 0..480 (h<256:W, else B)
    const int tid = threadIdx.x;
    {   // coalesced fp32 read, W/B are [k=256][h=256] row-major
        int r  = tid >> 3;                         // k 0..31
        int c4 = (tid & 7) * 4;                    // h 0..28
        const float* src = (h0 < 256)
            ? (W  + (size_t)(k0 + r) * H_F + h0 + c4)
            : (Bm + (size_t)(k0 + r) * H_F + (h0 - 256) + c4);
        float4 v = *(const float4*)src;
        t[r][c4 + 0] = f2bf(v.x); t[r][c4 + 1] = f2bf(v.y);
        t[r][c4 + 2] = f2bf(v.z); t[r][c4 + 3] = f2bf(v.w);
    }
    __syncthreads();
    {   // coalesced bf16 write, WBt row stride = 256 elements
        int hh  = tid >> 3;                        // 0..31
        int kk4 = (tid & 7) * 4;                   // 0..28
        ushort4 o;
        o.x = t[kk4 + 0][hh]; o.y = t[kk4 + 1][hh];
        o.z = t[kk4 + 2][hh]; o.w = t[kk4 + 3][hh];
        *(ushort4*)(WBt + (size_t)(h0 + hh) * D_F + k0 + kk4) = o;
    }
}

// ---------------- kernel 2: Y = bf16(vf) @ WBt^T, 64x512 tile -------------
// A: vf fp32 [NPAD,256], converted to bf16 during reg-staging.
// B: WBt[512 n][256 k] bf16 via global_load_lds (pre-swizzled source).
// 8 waves (2m x 4n), wave tile 32x128, BK=32, 8 k-steps, double-buffered.
__global__ __launch_bounds__(512, 4) void gemm_y(
    const float* __restrict__ vf,
    const unsigned short* __restrict__ WBt,
    unsigned short* __restrict__ Y) {
    __shared__ char Alds[2][4096];     // [64 m][32 k] bf16, XOR-swizzled
    __shared__ char Blds[2][32768];    // [512 n][32 k] bf16, XOR-swizzled
    const int bm   = blockIdx.x * 64;
    const int tid  = threadIdx.x;
    const int wave = tid >> 6, lane = tid & 63;
    const int wm   = wave >> 2, wn = wave & 3;

    f32x4 acc[2][8];
    const f32x4 fzero = {0.f, 0.f, 0.f, 0.f};
#pragma unroll
    for (int i = 0; i < 2; ++i)
#pragma unroll
        for (int j = 0; j < 8; ++j) acc[i][j] = fzero;

    // A staging: thread -> (row, 4 k-elems); clamp pad rows for safe reads
    const int ar = tid >> 3;                       // 0..63
    const int ak = (tid & 7) * 4;                  // 0..28
    const int arow_g = (bm + ar < N_V) ? bm + ar : N_V - 1;
    const float* aptr = vf + (size_t)arow_g * D_F + ak;
    const unsigned aP = ar * 64u + (((unsigned)ak * 2u) ^ (((unsigned)ar & 3u) << 4));

    // B staging: 4 x load16/thread; precompute swizzled source offsets
    unsigned boff[4];
#pragma unroll
    for (int i = 0; i < 4; ++i) {
        unsigned P = i * 8192u + tid * 16u;            // physical (linear dest)
        unsigned L = P ^ (((P >> 6) & 3u) << 4);       // logical byte
        boff[i] = (L >> 6) * 512u + (L & 63u);         // row*rowbytes + colbytes
    }

    float4 aReg;
    auto stageA_load = [&](int t) { aReg = *(const float4*)(aptr + t * 32); };
    auto stageA_write = [&](int buf) {
        ushort4 o;
        o.x = f2bf(aReg.x); o.y = f2bf(aReg.y);
        o.z = f2bf(aReg.z); o.w = f2bf(aReg.w);
        *(ushort4*)(Alds[buf] + aP) = o;
    };
    auto stageB = [&](int buf, int t) {
#pragma unroll
        for (int i = 0; i < 4; ++i)
            load16((const char*)WBt + boff[i] + t * 64,
                   Blds[buf] + i * 8192 + wave * 1024);
    };

    stageA_load(0); stageB(0, 0); stageA_write(0);
    __syncthreads();
    int cur = 0;
    for (int t = 0; t < 8; ++t) {
        if (t < 7) { stageA_load(t + 1); stageB(cur ^ 1, t + 1); }
        bf16x8 af[2];
#pragma unroll
        for (int mf = 0; mf < 2; ++mf) {
            unsigned r = wm * 32u + mf * 16u + (lane & 15);
            unsigned c = ((unsigned)lane >> 4) << 4;
            af[mf] = *(const bf16x8*)(Alds[cur] + r * 64 + (c ^ ((r & 3u) << 4)));
        }
#pragma unroll
        for (int nf = 0; nf < 8; ++nf) {
            unsigned r = wn * 128u + nf * 16u + (lane & 15);
            unsigned c = ((unsigned)lane >> 4) << 4;
            bf16x8 bfr = *(const bf16x8*)(Blds[cur] + r * 64 + (c ^ ((r & 3u) << 4)));
            acc[0][nf] = __builtin_amdgcn_mfma_f32_16x16x32_bf16(
                af[0], bfr, acc[0][nf], 0, 0, 0);
            acc[1][nf] = __builtin_amdgcn_mfma_f32_16x16x32_bf16(
                af[1], bfr, acc[1][nf], 0, 0, 0);
        }
        if (t < 7) stageA_write(cur ^ 1);   // vmcnt(4): waits A only
        __syncthreads();                    // drains vmcnt(0): next buf ready
        cur ^= 1;
    }

    // epilogue: Y bf16 store (pad rows hold clamped-copy garbage, never read)
#pragma unroll
    for (int mf = 0; mf < 2; ++mf) {
        int row0 = bm + wm * 32 + mf * 16 + ((lane >> 4) << 2);
#pragma unroll
        for (int nf = 0; nf < 8; ++nf) {
            int col = wn * 128 + nf * 16 + (lane & 15);
            f32x4 v = acc[mf][nf];
#pragma unroll
            for (int i = 0; i < 4; ++i)
                Y[(size_t)(row0 + i) * HK2 + col] = f2bf(v[i]);
        }
    }
}

// ---------------- kernel 3: gather + mean + add + relu --------------------
__global__ __launch_bounds__(256) void gather_out(
    const unsigned short* __restrict__ Y, const int* __restrict__ nbr,
    const int* __restrict__ lens, float* __restrict__ out) {
    const int wave = threadIdx.x >> 6;
    const int lane = threadIdx.x & 63;
    const int n = blockIdx.x * 4 + wave;
    if (n >= N_V) return;
    const int len = lens[n];
    const int idx = nbr[(size_t)n * KNB + (lane & 15)];
    const ushort4 y2 = *(const ushort4*)(Y + (size_t)n * HK2 + 256 + lane * 4);
    f32x4 acc = {0.f, 0.f, 0.f, 0.f};
#define ROW_(j) (*(const ushort4*)(Y + (size_t)(j) * HK2 + lane * 4))
#define ACC_(v) { acc[0] += bf2f(v.x); acc[1] += bf2f(v.y); \
                  acc[2] += bf2f(v.z); acc[3] += bf2f(v.w); }
    int k = 0;
    for (; k + 4 <= len; k += 4) {
        int j0 = __shfl(idx, k),     j1 = __shfl(idx, k + 1);
        int j2 = __shfl(idx, k + 2), j3 = __shfl(idx, k + 3);
        ushort4 v0 = ROW_(j0), v1 = ROW_(j1), v2 = ROW_(j2), v3 = ROW_(j3);
        ACC_(v0); ACC_(v1); ACC_(v2); ACC_(v3);
    }
    for (; k < len; ++k) {
        int j = __shfl(idx, k);
        ushort4 v = ROW_(j);
        ACC_(v);
    }
#undef ROW_
#undef ACC_
    const float inv = 1.0f / (float)(len > 0 ? len : 1);
    float4 o;
    o.x = fmaxf(fmaf(acc[0], inv, bf2f(y2.x)), 0.f);
    o.y = fmaxf(fmaf(acc[1], inv, bf2f(y2.y)), 0.f);
    o.z = fmaxf(fmaf(acc[2], inv, bf2f(y2.z)), 0.f);
    o.w = fmaxf(fmaf(acc[3], inv, bf2f(y2.w)), 0.f);
    *(float4*)(out + (size_t)n * H_F + lane * 4) = o;
}

extern "C" void kernel_launch(void* const* d_in, const int* in_sizes, int n_in,
                              void* d_out, int out_size, void* d_ws, size_t ws_size,
                              hipStream_t stream) {
    const float* vf   = (const float*)d_in[0];
    const int*   nbr  = (const int*)d_in[1];
    const int*   lens = (const int*)d_in[2];
    const float* W    = (const float*)d_in[3];
    const float* Bm   = (const float*)d_in[4];
    float* out = (float*)d_out;

    unsigned short* Y   = (unsigned short*)d_ws;                 // NPAD*512 bf16
    unsigned short* WBt = Y + (size_t)NPAD * HK2;                // 512*256 bf16

    hipLaunchKernelGGL(wbt_convert, dim3(8, 16), dim3(256), 0, stream, W, Bm, WBt);
    hipLaunchKernelGGL(gemm_y, dim3(NPAD / 64), dim3(512), 0, stream, vf, WBt, Y);
    hipLaunchKernelGGL(gather_out, dim3(N_V / 4), dim3(256), 0, stream,
                       Y, nbr, lens, out);
}